// Round 1
// baseline (314.894 us; speedup 1.0000x reference)
//
#include <hip/hip_runtime.h>

// Problem constants
#define BB 2
#define TT 2048
#define CC 1024
#define NH 16
#define HD 64
#define BT (BB*TT)          // 4096 rows

typedef __attribute__((ext_vector_type(8))) short bf16x8;
typedef __attribute__((ext_vector_type(4))) float floatx4;

__device__ __forceinline__ unsigned short f2bf(float f) {
    union { float f; unsigned int u; } v; v.f = f;
    unsigned int u = v.u;
    u = (u + 0x7fffu + ((u >> 16) & 1u)) >> 16;   // RNE
    return (unsigned short)u;
}

// ---------------- cast fp32 -> bf16, 4 elems/thread ----------------
__global__ __launch_bounds__(256) void cast_k(const float* __restrict__ in,
                                              unsigned short* __restrict__ out, int n4) {
    int i = blockIdx.x * 256 + threadIdx.x;
    if (i >= n4) return;
    float4 v = ((const float4*)in)[i];
    ushort4 o;
    o.x = f2bf(v.x); o.y = f2bf(v.y); o.z = f2bf(v.z); o.w = f2bf(v.w);
    ((ushort4*)out)[i] = o;
}

// ---------------- bf16 MFMA GEMM: C[M,N] = A[M,K] * Bt[N,K]^T ----------------
// 64x64 tile, 256 threads (4 waves), 16x16x32 MFMA.
__global__ __launch_bounds__(256) void gemm_bt_k(const unsigned short* __restrict__ A,
                                                 const unsigned short* __restrict__ Bt,
                                                 float* __restrict__ C, int M, int N, int K) {
    __shared__ __align__(16) unsigned short As[64][40];  // 32 + 8 pad
    __shared__ __align__(16) unsigned short Bs[64][40];
    const int tid  = threadIdx.x;
    const int wave = tid >> 6;
    const int lane = tid & 63;
    const int quad = lane >> 4;
    const int l16  = lane & 15;
    const int row0 = blockIdx.y * 64;
    const int col0 = blockIdx.x * 64;
    const int sr = tid >> 2;            // staging row 0..63
    const int sc = (tid & 3) * 8;       // staging col 0,8,16,24

    floatx4 acc[4];
    #pragma unroll
    for (int i = 0; i < 4; i++) acc[i] = (floatx4){0.f, 0.f, 0.f, 0.f};

    const unsigned short* Ap = A  + (size_t)(row0 + sr) * K + sc;
    const unsigned short* Bp = Bt + (size_t)(col0 + sr) * K + sc;

    for (int k0 = 0; k0 < K; k0 += 32) {
        __syncthreads();
        *(int4*)&As[sr][sc] = *(const int4*)(Ap + k0);
        *(int4*)&Bs[sr][sc] = *(const int4*)(Bp + k0);
        __syncthreads();
        bf16x8 a = *(const bf16x8*)&As[16 * wave + l16][quad * 8];
        #pragma unroll
        for (int cb = 0; cb < 4; cb++) {
            bf16x8 b = *(const bf16x8*)&Bs[16 * cb + l16][quad * 8];
            acc[cb] = __builtin_amdgcn_mfma_f32_16x16x32_bf16(a, b, acc[cb], 0, 0, 0);
        }
    }
    #pragma unroll
    for (int cb = 0; cb < 4; cb++) {
        #pragma unroll
        for (int r = 0; r < 4; r++) {
            int row = row0 + 16 * wave + quad * 4 + r;
            int col = col0 + 16 * cb + l16;
            C[(size_t)row * N + col] = acc[cb][r];
        }
    }
}

// ---------------- RoPE + layout: QKV fp32 [4096,3072] -> Qb,Kb [BH,T,D] bf16, Vt [BH,D,T] bf16 ----
__global__ __launch_bounds__(256) void rope_k(const float* __restrict__ QKV,
                                              unsigned short* __restrict__ Qb,
                                              unsigned short* __restrict__ Kb,
                                              unsigned short* __restrict__ Vt) {
    int idx = blockIdx.x * 256 + threadIdx.x;      // 0 .. 4096*512-1
    int j = idx & 31;              // rotation pair 0..31
    int h = (idx >> 5) & 15;
    int i = idx >> 9;              // row 0..4095 (b*T + t)
    int t = i & (TT - 1);
    int bh = (i >> 11) * NH + h;

    const float* base = QKV + (size_t)i * 3072 + h * 64;
    float q1 = base[j],        q2 = base[j + 32];
    float k1 = base[1024 + j], k2 = base[1024 + j + 32];
    float v1 = base[2048 + j], v2 = base[2048 + j + 32];

    float inv = powf(10000.0f, -(float)(2 * j) / 64.0f);
    float ang = (float)t * inv;
    float c = cosf(ang), s = sinf(ang);

    size_t qoff = ((size_t)bh * TT + t) * 64;
    Qb[qoff + j]      = f2bf(q1 * c - q2 * s);
    Qb[qoff + j + 32] = f2bf(q2 * c + q1 * s);
    Kb[qoff + j]      = f2bf(k1 * c - k2 * s);
    Kb[qoff + j + 32] = f2bf(k2 * c + k1 * s);

    size_t voff = (size_t)bh * 64;
    Vt[(voff + j) * TT + t]      = f2bf(v1);
    Vt[(voff + j + 32) * TT + t] = f2bf(v2);
}

// ---------------- flash attention: 64-query tile per block, online softmax ----------------
__global__ __launch_bounds__(256) void flash_k(const unsigned short* __restrict__ Qb,
                                               const unsigned short* __restrict__ Kb,
                                               const unsigned short* __restrict__ Vt,
                                               unsigned short* __restrict__ Yb) {
    __shared__ __align__(16) unsigned short Qs[64][72];
    __shared__ __align__(16) unsigned short Ks[64][72];
    __shared__ __align__(16) unsigned short Vs[64][72];   // rows = d, cols = key
    __shared__ __align__(16) unsigned short Ps[64][72];
    const int tid  = threadIdx.x;
    const int wave = tid >> 6;
    const int lane = tid & 63;
    const int quad = lane >> 4;
    const int l16  = lane & 15;
    const int qt = blockIdx.x;
    const int bh = blockIdx.y;
    const int q0 = qt * 64;
    const int sr = tid >> 2;            // 0..63
    const int sc = (tid & 3) * 16;      // 0,16,32,48

    {   // stage Q once
        const unsigned short* src = Qb + ((size_t)bh * TT + q0 + sr) * 64 + sc;
        *(int4*)&Qs[sr][sc]     = *(const int4*)src;
        *(int4*)&Qs[sr][sc + 8] = *(const int4*)(src + 8);
    }

    floatx4 accO[4];
    #pragma unroll
    for (int i = 0; i < 4; i++) accO[i] = (floatx4){0.f, 0.f, 0.f, 0.f};
    float m_i[4], l_i[4];
    #pragma unroll
    for (int r = 0; r < 4; r++) { m_i[r] = -1e30f; l_i[r] = 0.f; }
    const float scale = 0.125f;   // 1/sqrt(64)

    for (int kt = 0; kt <= qt; kt++) {
        __syncthreads();
        {   // stage K tile [key][d] and V tile [d][key]
            const unsigned short* ks = Kb + ((size_t)bh * TT + kt * 64 + sr) * 64 + sc;
            *(int4*)&Ks[sr][sc]     = *(const int4*)ks;
            *(int4*)&Ks[sr][sc + 8] = *(const int4*)(ks + 8);
            const unsigned short* vs = Vt + ((size_t)bh * 64 + sr) * TT + kt * 64 + sc;
            *(int4*)&Vs[sr][sc]     = *(const int4*)vs;
            *(int4*)&Vs[sr][sc + 8] = *(const int4*)(vs + 8);
        }
        __syncthreads();

        // S = Q K^T  (rows = q in wave's stripe, cols = key)
        floatx4 sacc[4];
        #pragma unroll
        for (int i = 0; i < 4; i++) sacc[i] = (floatx4){0.f, 0.f, 0.f, 0.f};
        #pragma unroll
        for (int kk = 0; kk < 64; kk += 32) {
            bf16x8 aq = *(const bf16x8*)&Qs[16 * wave + l16][kk + quad * 8];
            #pragma unroll
            for (int cb = 0; cb < 4; cb++) {
                bf16x8 bk = *(const bf16x8*)&Ks[16 * cb + l16][kk + quad * 8];
                sacc[cb] = __builtin_amdgcn_mfma_f32_16x16x32_bf16(aq, bk, sacc[cb], 0, 0, 0);
            }
        }

        // scale + causal mask (diag tile only)
        float sv[4][4];
        #pragma unroll
        for (int cb = 0; cb < 4; cb++) {
            #pragma unroll
            for (int r = 0; r < 4; r++) {
                float s = sacc[cb][r] * scale;
                if (kt == qt) {
                    int qi = 16 * wave + quad * 4 + r;
                    int ki = 16 * cb + l16;
                    if (ki > qi) s = -1e30f;
                }
                sv[cb][r] = s;
            }
        }

        // online softmax per row (rows live in lanes with same quad)
        #pragma unroll
        for (int r = 0; r < 4; r++) {
            float rm = fmaxf(fmaxf(sv[0][r], sv[1][r]), fmaxf(sv[2][r], sv[3][r]));
            rm = fmaxf(rm, __shfl_xor(rm, 1));
            rm = fmaxf(rm, __shfl_xor(rm, 2));
            rm = fmaxf(rm, __shfl_xor(rm, 4));
            rm = fmaxf(rm, __shfl_xor(rm, 8));
            float mnew = fmaxf(m_i[r], rm);
            float alpha = __expf(m_i[r] - mnew);
            m_i[r] = mnew;
            float rs = 0.f;
            #pragma unroll
            for (int cb = 0; cb < 4; cb++) {
                float p = __expf(sv[cb][r] - mnew);
                sv[cb][r] = p;
                rs += p;
            }
            rs += __shfl_xor(rs, 1);
            rs += __shfl_xor(rs, 2);
            rs += __shfl_xor(rs, 4);
            rs += __shfl_xor(rs, 8);
            l_i[r] = l_i[r] * alpha + rs;
            #pragma unroll
            for (int cb = 0; cb < 4; cb++) accO[cb][r] *= alpha;
        }

        // P: C-layout -> LDS (bf16); wave-private 16-row stripe, no cross-wave sharing
        #pragma unroll
        for (int cb = 0; cb < 4; cb++)
            #pragma unroll
            for (int r = 0; r < 4; r++)
                Ps[16 * wave + quad * 4 + r][16 * cb + l16] = f2bf(sv[cb][r]);

        // O += P * V  (A = P rows q; B = Vt rows d; k-dim = key)
        #pragma unroll
        for (int kk = 0; kk < 64; kk += 32) {
            bf16x8 ap = *(const bf16x8*)&Ps[16 * wave + l16][kk + quad * 8];
            #pragma unroll
            for (int cb = 0; cb < 4; cb++) {
                bf16x8 bv = *(const bf16x8*)&Vs[16 * cb + l16][kk + quad * 8];
                accO[cb] = __builtin_amdgcn_mfma_f32_16x16x32_bf16(ap, bv, accO[cb], 0, 0, 0);
            }
        }
    }

    // epilogue: O/l -> Yb [B,T,C] bf16  (C col = h*64 + d)
    int b = bh >> 4, h = bh & 15;
    #pragma unroll
    for (int cb = 0; cb < 4; cb++) {
        #pragma unroll
        for (int r = 0; r < 4; r++) {
            int trow = q0 + 16 * wave + quad * 4 + r;
            float o = accO[cb][r] / l_i[r];
            Yb[((size_t)b * TT + trow) * CC + h * 64 + 16 * cb + l16] = f2bf(o);
        }
    }
}

extern "C" void kernel_launch(void* const* d_in, const int* in_sizes, int n_in,
                              void* d_out, int out_size, void* d_ws, size_t ws_size,
                              hipStream_t stream) {
    (void)in_sizes; (void)n_in; (void)out_size; (void)ws_size;
    const float* x  = (const float*)d_in[0];
    const float* Wq = (const float*)d_in[1];
    const float* Wk = (const float*)d_in[2];
    const float* Wv = (const float*)d_in[3];
    const float* Wo = (const float*)d_in[4];
    float* out = (float*)d_out;
    char* ws = (char*)d_ws;

    // workspace layout (bytes)
    unsigned short* xb    = (unsigned short*)(ws + 0);                      //  8 MB: x bf16 [4096,1024]
    unsigned short* wqkvb = (unsigned short*)(ws + (8ull  << 20));          //  6 MB: Wq|Wk|Wv bf16 [3072,1024]
    unsigned short* wob   = (unsigned short*)(ws + (14ull << 20));          //  2 MB: Wo bf16 [1024,1024]
    float*          qkv   = (float*)         (ws + (16ull << 20));          // 48 MB: QKV fp32 [4096,3072]
    unsigned short* Qb    = (unsigned short*)(ws + (64ull << 20));          //  8 MB: [BH,T,D]
    unsigned short* Kb    = (unsigned short*)(ws + (72ull << 20));          //  8 MB: [BH,T,D]
    unsigned short* Vt    = (unsigned short*)(ws + (80ull << 20));          //  8 MB: [BH,D,T]
    unsigned short* Yb    = (unsigned short*)(ws + (88ull << 20));          //  8 MB: Y bf16 [4096,1024]

    cast_k<<<4096, 256, 0, stream>>>(x,  xb,             1048576);
    cast_k<<<1024, 256, 0, stream>>>(Wq, wqkvb,           262144);
    cast_k<<<1024, 256, 0, stream>>>(Wk, wqkvb + 1048576, 262144);
    cast_k<<<1024, 256, 0, stream>>>(Wv, wqkvb + 2097152, 262144);
    cast_k<<<1024, 256, 0, stream>>>(Wo, wob,             262144);

    gemm_bt_k<<<dim3(48, 64), 256, 0, stream>>>(xb, wqkvb, qkv, 4096, 3072, 1024);
    rope_k<<<8192, 256, 0, stream>>>(qkv, Qb, Kb, Vt);
    flash_k<<<dim3(32, 32), 256, 0, stream>>>(Qb, Kb, Vt, Yb);
    gemm_bt_k<<<dim3(16, 64), 256, 0, stream>>>(Yb, wob, out, 4096, 1024, 1024);
}

// Round 2
// 255.825 us; speedup vs baseline: 1.2309x; 1.2309x over previous
//
#include <hip/hip_runtime.h>

// Problem constants
#define BB 2
#define TT 2048
#define CC 1024
#define NH 16
#define HD 64
#define BT (BB*TT)          // 4096 rows

typedef __attribute__((ext_vector_type(8))) short bf16x8;
typedef __attribute__((ext_vector_type(4))) float floatx4;

__device__ __forceinline__ unsigned short f2bf(float f) {
    union { float f; unsigned int u; } v; v.f = f;
    unsigned int u = v.u;
    u = (u + 0x7fffu + ((u >> 16) & 1u)) >> 16;   // RNE
    return (unsigned short)u;
}

// ---------------- cast fp32 -> bf16, 4 elems/thread ----------------
__global__ __launch_bounds__(256) void cast_k(const float* __restrict__ in,
                                              unsigned short* __restrict__ out, int n4) {
    int i = blockIdx.x * 256 + threadIdx.x;
    if (i >= n4) return;
    float4 v = ((const float4*)in)[i];
    ushort4 o;
    o.x = f2bf(v.x); o.y = f2bf(v.y); o.z = f2bf(v.z); o.w = f2bf(v.w);
    ((ushort4*)out)[i] = o;
}

// ---------------- bf16 MFMA GEMM: C[M,N] = A[M,K] * Bt[N,K]^T ----------------
__global__ __launch_bounds__(256) void gemm_bt_k(const unsigned short* __restrict__ A,
                                                 const unsigned short* __restrict__ Bt,
                                                 float* __restrict__ C, int M, int N, int K) {
    __shared__ __align__(16) unsigned short As[64][40];
    __shared__ __align__(16) unsigned short Bs[64][40];
    const int tid  = threadIdx.x;
    const int wave = tid >> 6;
    const int lane = tid & 63;
    const int quad = lane >> 4;
    const int l16  = lane & 15;
    const int row0 = blockIdx.y * 64;
    const int col0 = blockIdx.x * 64;
    const int sr = tid >> 2;
    const int sc = (tid & 3) * 8;

    floatx4 acc[4];
    #pragma unroll
    for (int i = 0; i < 4; i++) acc[i] = (floatx4){0.f, 0.f, 0.f, 0.f};

    const unsigned short* Ap = A  + (size_t)(row0 + sr) * K + sc;
    const unsigned short* Bp = Bt + (size_t)(col0 + sr) * K + sc;

    for (int k0 = 0; k0 < K; k0 += 32) {
        __syncthreads();
        *(int4*)&As[sr][sc] = *(const int4*)(Ap + k0);
        *(int4*)&Bs[sr][sc] = *(const int4*)(Bp + k0);
        __syncthreads();
        bf16x8 a = *(const bf16x8*)&As[16 * wave + l16][quad * 8];
        #pragma unroll
        for (int cb = 0; cb < 4; cb++) {
            bf16x8 b = *(const bf16x8*)&Bs[16 * cb + l16][quad * 8];
            acc[cb] = __builtin_amdgcn_mfma_f32_16x16x32_bf16(a, b, acc[cb], 0, 0, 0);
        }
    }
    #pragma unroll
    for (int cb = 0; cb < 4; cb++) {
        #pragma unroll
        for (int r = 0; r < 4; r++) {
            int row = row0 + 16 * wave + quad * 4 + r;
            int col = col0 + 16 * cb + l16;
            C[(size_t)row * N + col] = acc[cb][r];
        }
    }
}

// ---------------- RoPE + layout, with LDS-transposed V ----------------
// grid (64 row-tiles, 16 heads). Each block: 64 rows x one head (64 cols).
// Outputs: Qb,Kb [BH,T,D] bf16 (coalesced), Vt [BH,D,T] bf16 (coalesced via LDS transpose).
__global__ __launch_bounds__(256) void rope_k(const float* __restrict__ QKV,
                                              unsigned short* __restrict__ Qb,
                                              unsigned short* __restrict__ Kb,
                                              unsigned short* __restrict__ Vt) {
    __shared__ __align__(16) unsigned short Vsh[64][70];   // stride 35 dwords (odd-ish, kills transpose conflicts)
    const int tid = threadIdx.x;
    const int rt = blockIdx.x;        // 0..63
    const int h  = blockIdx.y;        // 0..15
    const int sr = tid >> 2;          // 0..63 row in tile
    const int jg = (tid & 3) * 8;     // pair group: 8 pairs
    const int gi = rt * 64 + sr;      // global row in [0,4096)
    const int t  = gi & (TT - 1);
    const int b  = gi >> 11;
    const int bh = b * NH + h;

    const float* base = QKV + (size_t)gi * 3072 + h * 64;
    float q1[8], q2[8], k1[8], k2[8], v1[8], v2[8];
    *(float4*)&q1[0] = *(const float4*)(base + jg);
    *(float4*)&q1[4] = *(const float4*)(base + jg + 4);
    *(float4*)&q2[0] = *(const float4*)(base + jg + 32);
    *(float4*)&q2[4] = *(const float4*)(base + jg + 36);
    *(float4*)&k1[0] = *(const float4*)(base + 1024 + jg);
    *(float4*)&k1[4] = *(const float4*)(base + 1024 + jg + 4);
    *(float4*)&k2[0] = *(const float4*)(base + 1024 + jg + 32);
    *(float4*)&k2[4] = *(const float4*)(base + 1024 + jg + 36);
    *(float4*)&v1[0] = *(const float4*)(base + 2048 + jg);
    *(float4*)&v1[4] = *(const float4*)(base + 2048 + jg + 4);
    *(float4*)&v2[0] = *(const float4*)(base + 2048 + jg + 32);
    *(float4*)&v2[4] = *(const float4*)(base + 2048 + jg + 36);

    unsigned short qo1[8], qo2[8], ko1[8], ko2[8], vo1[8], vo2[8];
    #pragma unroll
    for (int jj = 0; jj < 8; jj++) {
        int j = jg + jj;
        float inv = exp2f(-(float)j * 0.41524101186092f);   // log2(10000)/32
        float ang = (float)t * inv;
        float c = cosf(ang), s = sinf(ang);
        qo1[jj] = f2bf(q1[jj] * c - q2[jj] * s);
        qo2[jj] = f2bf(q2[jj] * c + q1[jj] * s);
        ko1[jj] = f2bf(k1[jj] * c - k2[jj] * s);
        ko2[jj] = f2bf(k2[jj] * c + k1[jj] * s);
        vo1[jj] = f2bf(v1[jj]);
        vo2[jj] = f2bf(v2[jj]);
    }
    size_t ro = ((size_t)bh * TT + t) * 64;
    *(int4*)(Qb + ro + jg)      = *(int4*)&qo1[0];
    *(int4*)(Qb + ro + jg + 32) = *(int4*)&qo2[0];
    *(int4*)(Kb + ro + jg)      = *(int4*)&ko1[0];
    *(int4*)(Kb + ro + jg + 32) = *(int4*)&ko2[0];
    *(int4*)&Vsh[sr][jg]        = *(int4*)&vo1[0];
    *(int4*)&Vsh[sr][jg + 32]   = *(int4*)&vo2[0];

    __syncthreads();
    // transposed write: thread -> d row dr, t cols tc..tc+15
    const int dr = tid >> 2;
    const int tc = (tid & 3) * 16;
    unsigned short tv[16];
    #pragma unroll
    for (int i = 0; i < 16; i++) tv[i] = Vsh[tc + i][dr];
    const int t0 = (rt & 31) * 64;
    size_t vo = ((size_t)bh * 64 + dr) * TT + t0 + tc;
    *(int4*)(Vt + vo)     = *(int4*)&tv[0];
    *(int4*)(Vt + vo + 8) = *(int4*)&tv[8];
}

// ---------------- flash attention: 128-q tile, 32 q-rows/wave, no-max softmax ----------------
__global__ __launch_bounds__(256) void flash_k(const unsigned short* __restrict__ Qb,
                                               const unsigned short* __restrict__ Kb,
                                               const unsigned short* __restrict__ Vt,
                                               unsigned short* __restrict__ Yb) {
    __shared__ __align__(16) unsigned short Ks[64][72];
    __shared__ __align__(16) unsigned short Vs[64][72];
    __shared__ __align__(16) unsigned short Ps[128][72];
    const int tid  = threadIdx.x;
    const int wave = tid >> 6;
    const int lane = tid & 63;
    const int quad = lane >> 4;
    const int l16  = lane & 15;
    const int qt = 15 - (blockIdx.x >> 5);   // longest blocks dispatched first (LPT)
    const int bh = blockIdx.x & 31;
    const int q0 = qt * 128;
    const int sr = tid >> 2;
    const int sc = (tid & 3) * 16;
    const float SCLOG2 = 0.18033688011112f;  // (1/8) * log2(e)

    // Q fragments in registers, loaded straight from global (k-dim contiguous)
    bf16x8 qf[2][2];
    #pragma unroll
    for (int rb = 0; rb < 2; rb++) {
        int row = q0 + wave * 32 + rb * 16 + l16;
        const unsigned short* qp = Qb + ((size_t)bh * TT + row) * 64 + quad * 8;
        qf[rb][0] = *(const bf16x8*)(qp);
        qf[rb][1] = *(const bf16x8*)(qp + 32);
    }

    floatx4 accO[2][4];
    float lsum[2][4];
    #pragma unroll
    for (int rb = 0; rb < 2; rb++) {
        #pragma unroll
        for (int cb = 0; cb < 4; cb++) accO[rb][cb] = (floatx4){0.f, 0.f, 0.f, 0.f};
        #pragma unroll
        for (int r = 0; r < 4; r++) lsum[rb][r] = 0.f;
    }

    const int ktend = 2 * qt + 2;
    // prefetch tile 0
    const unsigned short* kp = Kb + ((size_t)bh * TT + sr) * 64 + sc;
    const unsigned short* vp = Vt + ((size_t)bh * 64 + sr) * TT + sc;
    int4 ka = *(const int4*)kp, kb2 = *(const int4*)(kp + 8);
    int4 va = *(const int4*)vp, vb2 = *(const int4*)(vp + 8);

    for (int kt = 0; kt < ktend; kt++) {
        __syncthreads();
        *(int4*)&Ks[sr][sc]     = ka;
        *(int4*)&Ks[sr][sc + 8] = kb2;
        *(int4*)&Vs[sr][sc]     = va;
        *(int4*)&Vs[sr][sc + 8] = vb2;
        __syncthreads();
        if (kt + 1 < ktend) {   // prefetch next tile into registers (overlaps compute)
            const unsigned short* kp2 = kp + (size_t)(kt + 1) * 64 * 64;
            const unsigned short* vp2 = vp + (kt + 1) * 64;
            ka  = *(const int4*)kp2; kb2 = *(const int4*)(kp2 + 8);
            va  = *(const int4*)vp2; vb2 = *(const int4*)(vp2 + 8);
        }

        // S = Q K^T
        floatx4 sacc[2][4];
        #pragma unroll
        for (int rb = 0; rb < 2; rb++)
            #pragma unroll
            for (int cb = 0; cb < 4; cb++) sacc[rb][cb] = (floatx4){0.f, 0.f, 0.f, 0.f};
        #pragma unroll
        for (int kk = 0; kk < 2; kk++) {
            bf16x8 bk[4];
            #pragma unroll
            for (int cb = 0; cb < 4; cb++)
                bk[cb] = *(const bf16x8*)&Ks[16 * cb + l16][kk * 32 + quad * 8];
            #pragma unroll
            for (int rb = 0; rb < 2; rb++)
                #pragma unroll
                for (int cb = 0; cb < 4; cb++)
                    sacc[rb][cb] = __builtin_amdgcn_mfma_f32_16x16x32_bf16(qf[rb][kk], bk[cb], sacc[rb][cb], 0, 0, 0);
        }

        // no-max softmax: p = exp(s/8), per-lane partial l
        const bool diag = (kt >= 2 * qt);
        #pragma unroll
        for (int rb = 0; rb < 2; rb++) {
            #pragma unroll
            for (int cb = 0; cb < 4; cb++) {
                #pragma unroll
                for (int r = 0; r < 4; r++) {
                    float p = exp2f(sacc[rb][cb][r] * SCLOG2);
                    if (diag) {
                        int qi = q0 + wave * 32 + rb * 16 + quad * 4 + r;
                        int ki = kt * 64 + cb * 16 + l16;
                        if (ki > qi) p = 0.f;
                    }
                    lsum[rb][r] += p;
                    Ps[wave * 32 + rb * 16 + quad * 4 + r][cb * 16 + l16] =
                        (unsigned short)((__float_as_uint(p) + 0x8000u) >> 16);
                }
            }
        }

        // O += P V   (Ps is wave-private: no barrier needed)
        #pragma unroll
        for (int kk = 0; kk < 2; kk++) {
            bf16x8 bv[4];
            #pragma unroll
            for (int cb = 0; cb < 4; cb++)
                bv[cb] = *(const bf16x8*)&Vs[16 * cb + l16][kk * 32 + quad * 8];
            #pragma unroll
            for (int rb = 0; rb < 2; rb++) {
                bf16x8 ap = *(const bf16x8*)&Ps[wave * 32 + rb * 16 + l16][kk * 32 + quad * 8];
                #pragma unroll
                for (int cb = 0; cb < 4; cb++)
                    accO[rb][cb] = __builtin_amdgcn_mfma_f32_16x16x32_bf16(ap, bv[cb], accO[rb][cb], 0, 0, 0);
            }
        }
    }

    // epilogue: reduce l across the 16 col-lanes, divide, store
    const int b = bh >> 4, h = bh & 15;
    #pragma unroll
    for (int rb = 0; rb < 2; rb++) {
        float linv[4];
        #pragma unroll
        for (int r = 0; r < 4; r++) {
            float l = lsum[rb][r];
            l += __shfl_xor(l, 1);
            l += __shfl_xor(l, 2);
            l += __shfl_xor(l, 4);
            l += __shfl_xor(l, 8);
            linv[r] = 1.0f / l;
        }
        #pragma unroll
        for (int cb = 0; cb < 4; cb++) {
            #pragma unroll
            for (int r = 0; r < 4; r++) {
                int trow = q0 + wave * 32 + rb * 16 + quad * 4 + r;
                float o = accO[rb][cb][r] * linv[r];
                Yb[((size_t)b * TT + trow) * CC + h * 64 + 16 * cb + l16] = f2bf(o);
            }
        }
    }
}

extern "C" void kernel_launch(void* const* d_in, const int* in_sizes, int n_in,
                              void* d_out, int out_size, void* d_ws, size_t ws_size,
                              hipStream_t stream) {
    (void)in_sizes; (void)n_in; (void)out_size; (void)ws_size;
    const float* x  = (const float*)d_in[0];
    const float* Wq = (const float*)d_in[1];
    const float* Wk = (const float*)d_in[2];
    const float* Wv = (const float*)d_in[3];
    const float* Wo = (const float*)d_in[4];
    float* out = (float*)d_out;
    char* ws = (char*)d_ws;

    unsigned short* xb    = (unsigned short*)(ws + 0);                      //  8 MB
    unsigned short* wqkvb = (unsigned short*)(ws + (8ull  << 20));          //  6 MB
    unsigned short* wob   = (unsigned short*)(ws + (14ull << 20));          //  2 MB
    float*          qkv   = (float*)         (ws + (16ull << 20));          // 48 MB
    unsigned short* Qb    = (unsigned short*)(ws + (64ull << 20));          //  8 MB [BH,T,D]
    unsigned short* Kb    = (unsigned short*)(ws + (72ull << 20));          //  8 MB [BH,T,D]
    unsigned short* Vt    = (unsigned short*)(ws + (80ull << 20));          //  8 MB [BH,D,T]
    unsigned short* Yb    = (unsigned short*)(ws + (88ull << 20));          //  8 MB

    cast_k<<<4096, 256, 0, stream>>>(x,  xb,             1048576);
    cast_k<<<1024, 256, 0, stream>>>(Wq, wqkvb,           262144);
    cast_k<<<1024, 256, 0, stream>>>(Wk, wqkvb + 1048576, 262144);
    cast_k<<<1024, 256, 0, stream>>>(Wv, wqkvb + 2097152, 262144);
    cast_k<<<1024, 256, 0, stream>>>(Wo, wob,             262144);

    gemm_bt_k<<<dim3(48, 64), 256, 0, stream>>>(xb, wqkvb, qkv, 4096, 3072, 1024);
    rope_k<<<dim3(64, 16), 256, 0, stream>>>(qkv, Qb, Kb, Vt);
    flash_k<<<512, 256, 0, stream>>>(Qb, Kb, Vt, Yb);
    gemm_bt_k<<<dim3(16, 64), 256, 0, stream>>>(Yb, wob, out, 4096, 1024, 1024);
}

// Round 3
// 218.423 us; speedup vs baseline: 1.4417x; 1.1712x over previous
//
#include <hip/hip_runtime.h>

// Problem constants
#define BB 2
#define TT 2048
#define CC 1024
#define NH 16
#define HD 64

typedef __attribute__((ext_vector_type(8))) short bf16x8;
typedef __attribute__((ext_vector_type(4))) float floatx4;

__device__ __forceinline__ unsigned short f2bf(float f) {
    union { float f; unsigned int u; } v; v.f = f;
    unsigned int u = v.u;
    u = (u + 0x7fffu + ((u >> 16) & 1u)) >> 16;   // RNE
    return (unsigned short)u;
}

typedef __attribute__((address_space(3))) unsigned char* lds_ptr_t;
typedef const __attribute__((address_space(1))) unsigned char* glob_ptr_t;
__device__ __forceinline__ void gll16(const void* g, void* l) {
    __builtin_amdgcn_global_load_lds((glob_ptr_t)g, (lds_ptr_t)l, 16, 0, 0);
}

// ---------------- cast fp32 -> bf16, 4 elems/thread ----------------
__global__ __launch_bounds__(256) void cast_k(const float* __restrict__ in,
                                              unsigned short* __restrict__ out, int n4) {
    int i = blockIdx.x * 256 + threadIdx.x;
    if (i >= n4) return;
    float4 v = ((const float4*)in)[i];
    ushort4 o;
    o.x = f2bf(v.x); o.y = f2bf(v.y); o.z = f2bf(v.z); o.w = f2bf(v.w);
    ((ushort4*)out)[i] = o;
}

// ---------------- m97-style GEMM: C[M,N] fp32 = A[M,K] * Bt[N,K]^T, 128x128 tile ----------------
__global__ __launch_bounds__(256) void gemm128_k(const unsigned short* __restrict__ A,
                                                 const unsigned short* __restrict__ Bt,
                                                 float* __restrict__ C, int M, int N, int K) {
    __shared__ __align__(16) unsigned short As[128][32];   // unpadded: global_load_lds layout
    __shared__ __align__(16) unsigned short Bs[128][32];
    const int tid  = threadIdx.x;
    const int wave = tid >> 6;
    const int lane = tid & 63;
    const int quad = lane >> 4;
    const int l16  = lane & 15;
    const int wr = (wave >> 1) * 64;      // wave's row offset in tile
    const int wc = (wave & 1) * 64;       // wave's col offset in tile
    const int row0 = blockIdx.y * 128;
    const int col0 = blockIdx.x * 128;
    const int srow = tid >> 2;            // staging row 0..63
    const int scol = (tid & 3) * 8;       // staging col 0,8,16,24

    const unsigned short* Ap0 = A  + (size_t)(row0 + srow) * K + scol;
    const unsigned short* Ap1 = A  + (size_t)(row0 + 64 + srow) * K + scol;
    const unsigned short* Bp0 = Bt + (size_t)(col0 + srow) * K + scol;
    const unsigned short* Bp1 = Bt + (size_t)(col0 + 64 + srow) * K + scol;

    floatx4 acc[4][4];
    #pragma unroll
    for (int i = 0; i < 4; i++)
        #pragma unroll
        for (int j = 0; j < 4; j++) acc[i][j] = (floatx4){0.f, 0.f, 0.f, 0.f};

    for (int k0 = 0; k0 < K; k0 += 32) {
        __syncthreads();
        gll16(Ap0 + k0, &As[srow][scol]);
        gll16(Ap1 + k0, &As[64 + srow][scol]);
        gll16(Bp0 + k0, &Bs[srow][scol]);
        gll16(Bp1 + k0, &Bs[64 + srow][scol]);
        __syncthreads();
        bf16x8 af[4], bfr[4];
        #pragma unroll
        for (int i = 0; i < 4; i++) af[i]  = *(const bf16x8*)&As[wr + 16 * i + l16][quad * 8];
        #pragma unroll
        for (int j = 0; j < 4; j++) bfr[j] = *(const bf16x8*)&Bs[wc + 16 * j + l16][quad * 8];
        #pragma unroll
        for (int i = 0; i < 4; i++)
            #pragma unroll
            for (int j = 0; j < 4; j++)
                acc[i][j] = __builtin_amdgcn_mfma_f32_16x16x32_bf16(af[i], bfr[j], acc[i][j], 0, 0, 0);
    }

    #pragma unroll
    for (int i = 0; i < 4; i++) {
        #pragma unroll
        for (int j = 0; j < 4; j++) {
            #pragma unroll
            for (int r = 0; r < 4; r++) {
                int row = row0 + wr + 16 * i + quad * 4 + r;
                int col = col0 + wc + 16 * j + l16;
                C[(size_t)row * N + col] = acc[i][j][r];
            }
        }
    }
}

// ---------------- RoPE + layout; V written key-permuted (pi(16c+l)=4l+c) and transposed ----------------
__global__ __launch_bounds__(256) void rope_k(const float* __restrict__ QKV,
                                              unsigned short* __restrict__ Qb,
                                              unsigned short* __restrict__ Kb,
                                              unsigned short* __restrict__ Vt) {
    __shared__ __align__(16) unsigned short Vsh[64][70];
    const int tid = threadIdx.x;
    const int rt = blockIdx.x;        // 0..63
    const int h  = blockIdx.y;        // 0..15
    const int sr = tid >> 2;          // 0..63 row in tile
    const int jg = (tid & 3) * 8;     // pair group: 8 pairs
    const int gi = rt * 64 + sr;      // global row in [0,4096)
    const int t  = gi & (TT - 1);
    const int b  = gi >> 11;
    const int bh = b * NH + h;

    const float* base = QKV + (size_t)gi * 3072 + h * 64;
    float q1[8], q2[8], k1[8], k2[8], v1[8], v2[8];
    *(float4*)&q1[0] = *(const float4*)(base + jg);
    *(float4*)&q1[4] = *(const float4*)(base + jg + 4);
    *(float4*)&q2[0] = *(const float4*)(base + jg + 32);
    *(float4*)&q2[4] = *(const float4*)(base + jg + 36);
    *(float4*)&k1[0] = *(const float4*)(base + 1024 + jg);
    *(float4*)&k1[4] = *(const float4*)(base + 1024 + jg + 4);
    *(float4*)&k2[0] = *(const float4*)(base + 1024 + jg + 32);
    *(float4*)&k2[4] = *(const float4*)(base + 1024 + jg + 36);
    *(float4*)&v1[0] = *(const float4*)(base + 2048 + jg);
    *(float4*)&v1[4] = *(const float4*)(base + 2048 + jg + 4);
    *(float4*)&v2[0] = *(const float4*)(base + 2048 + jg + 32);
    *(float4*)&v2[4] = *(const float4*)(base + 2048 + jg + 36);

    unsigned short qo1[8], qo2[8], ko1[8], ko2[8], vo1[8], vo2[8];
    #pragma unroll
    for (int jj = 0; jj < 8; jj++) {
        int j = jg + jj;
        float inv = exp2f(-(float)j * 0.41524101186092f);   // log2(10000)/32
        float ang = (float)t * inv;
        float c = cosf(ang), s = sinf(ang);
        qo1[jj] = f2bf(q1[jj] * c - q2[jj] * s);
        qo2[jj] = f2bf(q2[jj] * c + q1[jj] * s);
        ko1[jj] = f2bf(k1[jj] * c - k2[jj] * s);
        ko2[jj] = f2bf(k2[jj] * c + k1[jj] * s);
        vo1[jj] = f2bf(v1[jj]);
        vo2[jj] = f2bf(v2[jj]);
    }
    size_t ro = ((size_t)bh * TT + t) * 64;
    *(int4*)(Qb + ro + jg)      = *(int4*)&qo1[0];
    *(int4*)(Qb + ro + jg + 32) = *(int4*)&qo2[0];
    *(int4*)(Kb + ro + jg)      = *(int4*)&ko1[0];
    *(int4*)(Kb + ro + jg + 32) = *(int4*)&ko2[0];
    *(int4*)&Vsh[sr][jg]        = *(int4*)&vo1[0];
    *(int4*)&Vsh[sr][jg + 32]   = *(int4*)&vo2[0];

    __syncthreads();
    // transposed + permuted write: Vt[..][t0+x] = V[key t0 + 16*(x&3) + (x>>2)]
    const int dr = tid >> 2;
    const int tc = (tid & 3) * 16;
    unsigned short tv[16];
    #pragma unroll
    for (int i = 0; i < 16; i++) {
        int x = tc + i;
        tv[i] = Vsh[16 * (x & 3) + (x >> 2)][dr];
    }
    const int t0 = (rt & 31) * 64;
    size_t vo = ((size_t)bh * 64 + dr) * TT + t0 + tc;
    *(int4*)(Vt + vo)     = *(int4*)&tv[0];
    *(int4*)(Vt + vo + 8) = *(int4*)&tv[8];
}

// ---------------- flash attention: 128-q tile, split-2 over kt, unnormalized partials ----------------
__global__ __launch_bounds__(256) void flash_k(const unsigned short* __restrict__ Qb,
                                               const unsigned short* __restrict__ Kb,
                                               const unsigned short* __restrict__ Vt,
                                               float* __restrict__ O0, float* __restrict__ O1,
                                               float* __restrict__ L0, float* __restrict__ L1) {
    __shared__ __align__(16) unsigned short Ks[64][72];
    __shared__ __align__(16) unsigned short Vs[64][72];
    __shared__ __align__(16) unsigned short Ps[128][72];
    const int tid  = threadIdx.x;
    const int wave = tid >> 6;
    const int lane = tid & 63;
    const int quad = lane >> 4;
    const int l16  = lane & 15;
    const int qt    = 15 - (blockIdx.x >> 6);   // LPT: longest first
    const int inner = blockIdx.x & 63;
    const int bh    = inner >> 1;
    const int split = inner & 1;
    const int q0 = qt * 128;
    const int sr = tid >> 2;
    const int sc = (tid & 3) * 16;
    const float SCLOG2 = 0.18033688011112f;  // (1/8) * log2(e)

    // Q fragments straight from global (k-dim contiguous)
    bf16x8 qf[2][2];
    #pragma unroll
    for (int rb = 0; rb < 2; rb++) {
        int row = q0 + wave * 32 + rb * 16 + l16;
        const unsigned short* qp = Qb + ((size_t)bh * TT + row) * 64 + quad * 8;
        qf[rb][0] = *(const bf16x8*)(qp);
        qf[rb][1] = *(const bf16x8*)(qp + 32);
    }

    floatx4 accO[2][4];
    float lsum[2][4];
    #pragma unroll
    for (int rb = 0; rb < 2; rb++) {
        #pragma unroll
        for (int cb = 0; cb < 4; cb++) accO[rb][cb] = (floatx4){0.f, 0.f, 0.f, 0.f};
        #pragma unroll
        for (int r = 0; r < 4; r++) lsum[rb][r] = 0.f;
    }

    const int kt0 = split * (qt + 1);
    const int kt1 = kt0 + qt + 1;           // each split: exactly qt+1 tiles
    const unsigned short* kbase = Kb + (size_t)bh * TT * 64;
    const unsigned short* vbase = Vt + (size_t)bh * 64 * TT;

    // prefetch first tile
    const unsigned short* kp = kbase + ((size_t)(kt0 * 64) + sr) * 64 + sc;
    const unsigned short* vp = vbase + (size_t)sr * TT + kt0 * 64 + sc;
    int4 ka = *(const int4*)kp, kb2 = *(const int4*)(kp + 8);
    int4 va = *(const int4*)vp, vb2 = *(const int4*)(vp + 8);

    for (int kt = kt0; kt < kt1; kt++) {
        __syncthreads();
        *(int4*)&Ks[sr][sc]     = ka;
        *(int4*)&Ks[sr][sc + 8] = kb2;
        *(int4*)&Vs[sr][sc]     = va;
        *(int4*)&Vs[sr][sc + 8] = vb2;
        __syncthreads();
        if (kt + 1 < kt1) {   // register prefetch of next tile
            const unsigned short* kp2 = kbase + ((size_t)((kt + 1) * 64) + sr) * 64 + sc;
            const unsigned short* vp2 = vbase + (size_t)sr * TT + (kt + 1) * 64 + sc;
            ka  = *(const int4*)kp2; kb2 = *(const int4*)(kp2 + 8);
            va  = *(const int4*)vp2; vb2 = *(const int4*)(vp2 + 8);
        }

        // S = Q K^T
        floatx4 sacc[2][4];
        #pragma unroll
        for (int rb = 0; rb < 2; rb++)
            #pragma unroll
            for (int cb = 0; cb < 4; cb++) sacc[rb][cb] = (floatx4){0.f, 0.f, 0.f, 0.f};
        #pragma unroll
        for (int kk = 0; kk < 2; kk++) {
            bf16x8 bk[4];
            #pragma unroll
            for (int cb = 0; cb < 4; cb++)
                bk[cb] = *(const bf16x8*)&Ks[16 * cb + l16][kk * 32 + quad * 8];
            #pragma unroll
            for (int rb = 0; rb < 2; rb++)
                #pragma unroll
                for (int cb = 0; cb < 4; cb++)
                    sacc[rb][cb] = __builtin_amdgcn_mfma_f32_16x16x32_bf16(qf[rb][kk], bk[cb], sacc[rb][cb], 0, 0, 0);
        }

        // p = exp2(s*c); packed write into permuted Ps cols (col 4*l16+cb = pi(16cb+l16))
        const bool diag = (kt >= 2 * qt);
        #pragma unroll
        for (int rb = 0; rb < 2; rb++) {
            #pragma unroll
            for (int r = 0; r < 4; r++) {
                float p[4];
                #pragma unroll
                for (int cb = 0; cb < 4; cb++) {
                    float pv = __builtin_amdgcn_exp2f(sacc[rb][cb][r] * SCLOG2);
                    if (diag) {
                        int qi = q0 + wave * 32 + rb * 16 + quad * 4 + r;
                        int ki = kt * 64 + cb * 16 + l16;
                        if (ki > qi) pv = 0.f;
                    }
                    lsum[rb][r] += pv;
                    p[cb] = pv;
                }
                unsigned lo = ((__float_as_uint(p[0]) + 0x8000u) >> 16) |
                              ((__float_as_uint(p[1]) + 0x8000u) & 0xffff0000u);
                unsigned hi = ((__float_as_uint(p[2]) + 0x8000u) >> 16) |
                              ((__float_as_uint(p[3]) + 0x8000u) & 0xffff0000u);
                uint2 pk; pk.x = lo; pk.y = hi;
                *(uint2*)&Ps[wave * 32 + rb * 16 + quad * 4 + r][l16 * 4] = pk;
            }
        }

        // O += P V   (Ps wave-private; k order matches V permutation)
        #pragma unroll
        for (int kk = 0; kk < 2; kk++) {
            bf16x8 bv[4];
            #pragma unroll
            for (int cb = 0; cb < 4; cb++)
                bv[cb] = *(const bf16x8*)&Vs[16 * cb + l16][kk * 32 + quad * 8];
            #pragma unroll
            for (int rb = 0; rb < 2; rb++) {
                bf16x8 ap = *(const bf16x8*)&Ps[wave * 32 + rb * 16 + l16][kk * 32 + quad * 8];
                #pragma unroll
                for (int cb = 0; cb < 4; cb++)
                    accO[rb][cb] = __builtin_amdgcn_mfma_f32_16x16x32_bf16(ap, bv[cb], accO[rb][cb], 0, 0, 0);
            }
        }
    }

    // epilogue: store unnormalized partials
    float* Op = split ? O1 : O0;
    float* Lp = split ? L1 : L0;
    #pragma unroll
    for (int rb = 0; rb < 2; rb++) {
        #pragma unroll
        for (int r = 0; r < 4; r++) {
            float l = lsum[rb][r];
            l += __shfl_xor(l, 1);
            l += __shfl_xor(l, 2);
            l += __shfl_xor(l, 4);
            l += __shfl_xor(l, 8);
            int row = q0 + wave * 32 + rb * 16 + quad * 4 + r;
            if (l16 == 0) Lp[(size_t)bh * TT + row] = l;
        }
        #pragma unroll
        for (int cb = 0; cb < 4; cb++) {
            #pragma unroll
            for (int r = 0; r < 4; r++) {
                int row = q0 + wave * 32 + rb * 16 + quad * 4 + r;
                Op[((size_t)bh * TT + row) * 64 + 16 * cb + l16] = accO[rb][cb][r];
            }
        }
    }
}

// ---------------- combine: Yb = (O0+O1)/(l0+l1), bf16 [B,T,C] ----------------
__global__ __launch_bounds__(256) void combine_k(const float* __restrict__ O0,
                                                 const float* __restrict__ O1,
                                                 const float* __restrict__ L0,
                                                 const float* __restrict__ L1,
                                                 unsigned short* __restrict__ Yb) {
    int idx = blockIdx.x * 256 + threadIdx.x;   // 0 .. 32*2048*16-1
    int dg  = idx & 15;
    int row = idx >> 4;                          // bh*2048 + t
    float inv = 1.0f / (L0[row] + L1[row]);
    float4 a = ((const float4*)O0)[idx];
    float4 b = ((const float4*)O1)[idx];
    ushort4 o;
    o.x = f2bf((a.x + b.x) * inv);
    o.y = f2bf((a.y + b.y) * inv);
    o.z = f2bf((a.z + b.z) * inv);
    o.w = f2bf((a.w + b.w) * inv);
    int bh = row >> 11, t = row & (TT - 1);
    int bb = bh >> 4, h = bh & 15;
    *(ushort4*)(Yb + ((size_t)(bb * TT + t)) * CC + h * 64 + dg * 4) = o;
}

extern "C" void kernel_launch(void* const* d_in, const int* in_sizes, int n_in,
                              void* d_out, int out_size, void* d_ws, size_t ws_size,
                              hipStream_t stream) {
    (void)in_sizes; (void)n_in; (void)out_size; (void)ws_size;
    const float* x  = (const float*)d_in[0];
    const float* Wq = (const float*)d_in[1];
    const float* Wk = (const float*)d_in[2];
    const float* Wv = (const float*)d_in[3];
    const float* Wo = (const float*)d_in[4];
    float* out = (float*)d_out;
    char* ws = (char*)d_ws;

    unsigned short* xb    = (unsigned short*)(ws + 0);                      //  8 MB
    unsigned short* wqkvb = (unsigned short*)(ws + (8ull  << 20));          //  6 MB
    unsigned short* wob   = (unsigned short*)(ws + (14ull << 20));          //  2 MB
    float*          qkv   = (float*)         (ws + (16ull << 20));          // 48 MB (dead after rope_k)
    unsigned short* Qb    = (unsigned short*)(ws + (64ull << 20));          //  8 MB [BH,T,D]
    unsigned short* Kb    = (unsigned short*)(ws + (72ull << 20));          //  8 MB [BH,T,D]
    unsigned short* Vt    = (unsigned short*)(ws + (80ull << 20));          //  8 MB [BH,D,T] key-permuted
    unsigned short* Yb    = (unsigned short*)(ws + (88ull << 20));          //  8 MB
    // flash partials alias the dead qkv region (stream-ordered, safe)
    float* O0 = (float*)(ws + (16ull << 20));                               // 16 MB
    float* O1 = (float*)(ws + (32ull << 20));                               // 16 MB
    float* L0 = (float*)(ws + (48ull << 20));                               // 256 KB
    float* L1 = (float*)(ws + (48ull << 20) + (256ull << 10));              // 256 KB

    cast_k<<<4096, 256, 0, stream>>>(x,  xb,             1048576);
    cast_k<<<1024, 256, 0, stream>>>(Wq, wqkvb,           262144);
    cast_k<<<1024, 256, 0, stream>>>(Wk, wqkvb + 1048576, 262144);
    cast_k<<<1024, 256, 0, stream>>>(Wv, wqkvb + 2097152, 262144);
    cast_k<<<1024, 256, 0, stream>>>(Wo, wob,             262144);

    gemm128_k<<<dim3(24, 32), 256, 0, stream>>>(xb, wqkvb, qkv, 4096, 3072, 1024);
    rope_k<<<dim3(64, 16), 256, 0, stream>>>(qkv, Qb, Kb, Vt);
    flash_k<<<1024, 256, 0, stream>>>(Qb, Kb, Vt, O0, O1, L0, L1);
    combine_k<<<4096, 256, 0, stream>>>(O0, O1, L0, L1, Yb);
    gemm128_k<<<dim3(8, 32), 256, 0, stream>>>(Yb, wob, out, 4096, 1024, 1024);
}